// Round 1
// 184.433 us; speedup vs baseline: 1.0266x; 1.0266x over previous
//
#include <hip/hip_runtime.h>
#include <hip/hip_bf16.h>

// Problem constants
#define S_LEN 4096
#define EMB   1024
#define NH    16
#define HD    64
#define WIN   256
#define SCALE 0.125f

typedef __attribute__((ext_vector_type(8))) short short8;          // 8 bf16
typedef __attribute__((ext_vector_type(4))) float f32x4;           // 4 fp32
typedef __attribute__((ext_vector_type(4))) unsigned short us4;    // 4 bf16

__device__ inline unsigned short f2b(float x) {
    __hip_bfloat16 b = __float2bfloat16(x);
    return *reinterpret_cast<unsigned short*>(&b);
}

__device__ inline void gld_lds16(const unsigned short* g, unsigned short* l) {
    __builtin_amdgcn_global_load_lds(
        (const __attribute__((address_space(1))) unsigned int*)g,
        (__attribute__((address_space(3))) unsigned int*)l,
        16, 0, 0);
}

// ---------------------------------------------------------------- fused prep
__device__ inline void transpose_tile(const float* __restrict__ in,
                                      unsigned short* __restrict__ out,
                                      int R, int C, int bx, int by,
                                      unsigned short* t) {
    const int tid = threadIdx.x;
    const int r0 = by * 64, c0 = bx * 64;

    const int rr = tid >> 4, cc = (tid & 15) * 4;
    #pragma unroll
    for (int i = 0; i < 4; ++i) {
        float4 v = *reinterpret_cast<const float4*>(&in[(size_t)(r0 + rr + i * 16) * C + c0 + cc]);
        t[(cc + 0) * 72 + rr + i * 16] = f2b(v.x);
        t[(cc + 1) * 72 + rr + i * 16] = f2b(v.y);
        t[(cc + 2) * 72 + rr + i * 16] = f2b(v.z);
        t[(cc + 3) * 72 + rr + i * 16] = f2b(v.w);
    }
    __syncthreads();

    const int wr = tid >> 2, wk = (tid & 3) * 16;
    #pragma unroll
    for (int p = 0; p < 2; ++p)
        *reinterpret_cast<uint4*>(&out[(size_t)(c0 + wr) * R + r0 + wk + p * 8]) =
            *reinterpret_cast<const uint4*>(&t[wr * 72 + wk + p * 8]);
}

__global__ __launch_bounds__(256) void prep(const float* __restrict__ x,
                                            unsigned short* __restrict__ xb,
                                            const float* __restrict__ w_qkv,
                                            unsigned short* __restrict__ wqkvT,
                                            const float* __restrict__ w_out,
                                            unsigned short* __restrict__ woutT) {
    __shared__ alignas(16) unsigned short t[64 * 72];
    const int b = blockIdx.x;
    if (b < 768) {
        transpose_tile(w_qkv, wqkvT, EMB, 3 * EMB, b % 48, b / 48, t);
    } else if (b < 1024) {
        const int bb = b - 768;
        transpose_tile(w_out, woutT, EMB, EMB, bb & 15, bb >> 4, t);
    } else {
        const size_t tt = (size_t)(b - 1024) * 256 + threadIdx.x;
        const float4* s4 = reinterpret_cast<const float4*>(x) + tt * 4;
        float4 v0 = s4[0], v1 = s4[1], v2 = s4[2], v3 = s4[3];
        us4 p0 = {f2b(v0.x), f2b(v0.y), f2b(v0.z), f2b(v0.w)};
        us4 p1 = {f2b(v1.x), f2b(v1.y), f2b(v1.z), f2b(v1.w)};
        us4 p2 = {f2b(v2.x), f2b(v2.y), f2b(v2.z), f2b(v2.w)};
        us4 p3 = {f2b(v3.x), f2b(v3.y), f2b(v3.z), f2b(v3.w)};
        us4* d = reinterpret_cast<us4*>(xb) + tt * 4;
        d[0] = p0; d[1] = p1; d[2] = p2; d[3] = p3;
    }
}

// ---------------------------------------------------------------- swizzled-DMA GEMM (kept for out-proj, MODE 0)
template <int MODE, int BN>
__global__ __launch_bounds__(256) void gemm_bt(const unsigned short* __restrict__ A,
                                               const unsigned short* __restrict__ Bt,
                                               void* __restrict__ Cout,
                                               unsigned short* __restrict__ vT,
                                               int M, int N, int K) {
    constexpr int SMEM_ELEMS = (MODE == 1) ? 17408 : 8192 + BN * 64;
    constexpr int NJ = BN / 32;
    __shared__ alignas(16) unsigned short smem[SMEM_ELEMS];
    unsigned short* As = smem;           // [128][64] swizzled
    unsigned short* Bs = smem + 8192;    // [BN][64] swizzled

    const int tid  = threadIdx.x;
    const int lane = tid & 63;
    const int w    = tid >> 6;
    const int quad = lane >> 4;
    const int l16  = lane & 15;

    const int m0 = blockIdx.y * 128;
    const int n0 = blockIdx.x * BN;
    const int m_off = (w & 1) * 64;
    const int n_off = (w >> 1) * (BN / 2);

    const int s_row = tid >> 3;
    const int s_c0  = tid & 7;

    f32x4 acc[4][NJ];
    #pragma unroll
    for (int i = 0; i < 4; ++i)
        #pragma unroll
        for (int j = 0; j < NJ; ++j)
            acc[i][j] = (f32x4){0.f, 0.f, 0.f, 0.f};

    for (int bk = 0; bk < K; bk += 64) {
        __syncthreads();
        #pragma unroll
        for (int p = 0; p < 4; ++p) {
            const int row = p * 32 + s_row;
            const int c   = s_c0 ^ (row & 7);
            gld_lds16(A + (size_t)(m0 + row) * K + bk + c * 8,
                      As + (p * 256 + w * 64) * 8);
        }
        #pragma unroll
        for (int p = 0; p < BN / 32; ++p) {
            const int row = p * 32 + s_row;
            const int c   = s_c0 ^ (row & 7);
            gld_lds16(Bt + (size_t)(n0 + row) * K + bk + c * 8,
                      Bs + (p * 256 + w * 64) * 8);
        }
        __syncthreads();

        #pragma unroll
        for (int ks = 0; ks < 2; ++ks) {
            short8 af[4], bf[NJ];
            #pragma unroll
            for (int i = 0; i < 4; ++i) {
                const int r = m_off + i * 16 + l16;
                af[i] = *reinterpret_cast<const short8*>(
                    &As[r * 64 + ((ks * 4 + quad) ^ (r & 7)) * 8]);
            }
            #pragma unroll
            for (int j = 0; j < NJ; ++j) {
                const int r = n_off + j * 16 + l16;
                bf[j] = *reinterpret_cast<const short8*>(
                    &Bs[r * 64 + ((ks * 4 + quad) ^ (r & 7)) * 8]);
            }
            #pragma unroll
            for (int i = 0; i < 4; ++i)
                #pragma unroll
                for (int j = 0; j < NJ; ++j)
                    acc[i][j] = __builtin_amdgcn_mfma_f32_16x16x32_bf16(
                        af[i], bf[j], acc[i][j], 0, 0, 0);
        }
    }

    if (MODE == 0) {
        float* C = (float*)Cout;
        #pragma unroll
        for (int i = 0; i < 4; ++i)
            #pragma unroll
            for (int r = 0; r < 4; ++r) {
                const size_t row = m0 + m_off + i * 16 + quad * 4 + r;
                #pragma unroll
                for (int j = 0; j < NJ; ++j)
                    C[row * N + n0 + n_off + j * 16 + l16] = acc[i][j][r];
            }
    } else if (n0 < 2048) {
        const float sc = (n0 < 1024) ? SCALE : 1.0f;
        unsigned short* C = (unsigned short*)Cout;
        #pragma unroll
        for (int i = 0; i < 4; ++i)
            #pragma unroll
            for (int r = 0; r < 4; ++r) {
                const size_t row = m0 + m_off + i * 16 + quad * 4 + r;
                #pragma unroll
                for (int j = 0; j < NJ; ++j)
                    C[row * N + n0 + n_off + j * 16 + l16] = f2b(acc[i][j][r] * sc);
            }
    } else {
        __syncthreads();
        #pragma unroll
        for (int i = 0; i < 4; ++i) {
            const int ss = m_off + i * 16 + quad * 4;
            #pragma unroll
            for (int j = 0; j < NJ; ++j) {
                const int dd = n_off + j * 16 + l16;
                us4 pk = {f2b(acc[i][j][0]), f2b(acc[i][j][1]),
                          f2b(acc[i][j][2]), f2b(acc[i][j][3])};
                *reinterpret_cast<us4*>(&smem[dd * 136 + ss]) = pk;
            }
        }
        __syncthreads();
        #pragma unroll
        for (int p = 0; p < 8; ++p) {
            const int t  = p * 256 + tid;
            const int dd = t >> 4;
            const int sc2 = (t & 15) * 8;
            *reinterpret_cast<uint4*>(&vT[(size_t)(n0 - 2048 + dd) * S_LEN + m0 + sc2]) =
                *reinterpret_cast<const uint4*>(&smem[dd * 136 + sc2]);
        }
    }
}

// ---------------------------------------------------------------- QKV GEMM: 256x256 tile, counted-vmcnt pipeline
// C[4096,3072] = xb[4096,1024] @ wqkvT[3072,1024]^T, bf16.
// 8 waves (2M x 4N), per-wave 128x64 output, acc[8][4].
// K processed in 32-wide phases (32 phases). LDS = 2 buffers x {A,B} x
// {k-half0, k-half1}, each half [row 256][chunk 4] of 16B chunks, chunk slot
// cp = c4 ^ ((row>>1)&3)  (frag reads hit 8 distinct bank groups -> 2-way, free;
// collapses to per-thread constant quad^((l16>>1)&3)).
// Schedule: phase p reads need(p) = half (p&1) of buf ((p>>1)&1); STAGE(q) is
// issued at phase q-3 (3-phase lookahead ~ >=1000cy covers HBM latency).
// Each phase ends  s_waitcnt vmcnt(8); s_barrier  -- wait THEN barrier makes
// the oldest in-flight stage-group's completion a collective guarantee
// (race-free counted vmcnt; never drains to 0 in the main loop).
// Region staged at phase p was last read at phase p-1 (barrier-separated).
__global__ __launch_bounds__(512) void gemm_qkv(const unsigned short* __restrict__ A,
                                                const unsigned short* __restrict__ Bt,
                                                unsigned short* __restrict__ C,
                                                unsigned short* __restrict__ vT) {
    __shared__ alignas(16) unsigned short smem[65536];   // 128 KiB

    constexpr int K = EMB;       // 1024
    const int tid  = threadIdx.x;
    const int lane = tid & 63;
    const int w    = tid >> 6;
    const int quad = lane >> 4;
    const int l16  = lane & 15;
    const int wr   = w >> 2, wc = w & 3;
    const int wm0  = wr * 128, wn0 = wc * 64;

    // XCD swizzle: 192 blocks = 8 XCDs x 24 (192 % 8 == 0 -> bijective)
    const int raw = blockIdx.x;
    const int s   = (raw & 7) * 24 + (raw >> 3);
    const int by  = s / 12, bx = s % 12;
    const int m0  = by * 256, n0 = bx * 256;

    // staging source (per lane): rep0 row = tid>>2, rep1 = +128; chunk swizzle
    const int srow = tid >> 2;
    const int scp  = tid & 3;
    const int sc4  = scp ^ ((srow >> 1) & 3);
    const unsigned short* pA = A  + (size_t)(m0 + srow) * K + sc4 * 8;
    const unsigned short* pB = Bt + (size_t)(n0 + srow) * K + sc4 * 8;
    const int dls = (w * 64) * 8;   // wave-uniform LDS dest offset (elems), rep0

    auto STAGE = [&](int q) {
        unsigned short* dA = smem + ((q >> 1) & 1) * 32768 + (q & 1) * 8192 + dls;
        unsigned short* dB = dA + 16384;
        const int gk = q * 32;
        gld_lds16(pA + gk, dA);
        gld_lds16(pA + (size_t)128 * K + gk, dA + 4096);
        gld_lds16(pB + gk, dB);
        gld_lds16(pB + (size_t)128 * K + gk, dB + 4096);
    };

    // fragment read offsets (phase-independent)
    const int cpf = quad ^ ((l16 >> 1) & 3);
    const int oA  = (wm0 + l16) * 32 + cpf * 8;   // + i*512
    const int oB  = (wn0 + l16) * 32 + cpf * 8;   // + j*512

    f32x4 acc[8][4];
    #pragma unroll
    for (int i = 0; i < 8; ++i)
        #pragma unroll
        for (int j = 0; j < 4; ++j)
            acc[i][j] = (f32x4){0.f, 0.f, 0.f, 0.f};

    auto PHASE = [&](int p, bool stage_ok) {
        const unsigned short* Ab = smem + ((p >> 1) & 1) * 32768 + (p & 1) * 8192;
        const unsigned short* Bb = Ab + 16384;
        short8 af[8], bf[4];
        #pragma unroll
        for (int i = 0; i < 8; ++i)
            af[i] = *reinterpret_cast<const short8*>(&Ab[oA + i * 512]);
        #pragma unroll
        for (int j = 0; j < 4; ++j)
            bf[j] = *reinterpret_cast<const short8*>(&Bb[oB + j * 512]);
        if (stage_ok) STAGE(p + 3);
        __builtin_amdgcn_sched_barrier(0);   // keep VMEM issue ahead of MFMA cluster
        __builtin_amdgcn_s_setprio(1);
        #pragma unroll
        for (int i = 0; i < 8; ++i)
            #pragma unroll
            for (int j = 0; j < 4; ++j)
                acc[i][j] = __builtin_amdgcn_mfma_f32_16x16x32_bf16(af[i], bf[j], acc[i][j], 0, 0, 0);
        __builtin_amdgcn_s_setprio(0);
    };

    // prologue: stage phases 0,1,2 (12 loads), wait oldest 4 (phase 0) landed
    STAGE(0); STAGE(1); STAGE(2);
    asm volatile("s_waitcnt vmcnt(8)" ::: "memory");
    __builtin_amdgcn_s_barrier();

    for (int pp = 0; pp < 28; pp += 4) {
        #pragma unroll
        for (int e = 0; e < 4; ++e) {
            PHASE(pp + e, true);              // stages q = p+3 (max 30 here)
            asm volatile("s_waitcnt vmcnt(8)" ::: "memory");
            __builtin_amdgcn_s_barrier();
        }
    }
    PHASE(28, true);                          // stages q = 31 (last)
    asm volatile("s_waitcnt vmcnt(8)" ::: "memory");
    __builtin_amdgcn_s_barrier();
    PHASE(29, false);
    asm volatile("s_waitcnt vmcnt(4)" ::: "memory");
    __builtin_amdgcn_s_barrier();
    PHASE(30, false);
    asm volatile("s_waitcnt vmcnt(0)" ::: "memory");
    __builtin_amdgcn_s_barrier();
    PHASE(31, false);
    __builtin_amdgcn_s_barrier();             // all LDS frag reads done before reuse

    const int sec = n0 >> 10;                 // 0=Q, 1=K, 2=V
    if (sec < 2) {
        const float sc = (sec == 0) ? SCALE : 1.0f;
        #pragma unroll
        for (int i = 0; i < 8; ++i) {
            #pragma unroll
            for (int r = 0; r < 4; ++r) {
                const size_t row = (size_t)(m0 + wm0 + i * 16 + quad * 4 + r) * 3072;
                #pragma unroll
                for (int j = 0; j < 4; ++j)
                    C[row + n0 + wn0 + j * 16 + l16] = f2b(acc[i][j][r] * sc);
            }
        }
    } else {
        // V: transpose 256x256 via LDS (chunk slot = sc ^ (d&31)), write vT[d][s]
        #pragma unroll
        for (int i = 0; i < 8; ++i) {
            const int ss = wm0 + i * 16 + quad * 4;
            const int sc0 = ss >> 3, se = ss & 7;
            #pragma unroll
            for (int j = 0; j < 4; ++j) {
                const int d = wn0 + j * 16 + l16;
                us4 pk = {f2b(acc[i][j][0]), f2b(acc[i][j][1]),
                          f2b(acc[i][j][2]), f2b(acc[i][j][3])};
                *reinterpret_cast<us4*>(&smem[d * 256 + ((sc0 ^ (d & 31)) << 3) + se]) = pk;
            }
        }
        __builtin_amdgcn_s_barrier();
        const int vb = n0 - 2048;
        #pragma unroll
        for (int rep = 0; rep < 16; ++rep) {
            const int idx = rep * 512 + tid;
            const int d = idx >> 5, scr = idx & 31;
            *reinterpret_cast<uint4*>(&vT[(size_t)(vb + d) * S_LEN + m0 + scr * 8]) =
                *reinterpret_cast<const uint4*>(&smem[d * 256 + ((scr ^ (d & 31)) << 3)]);
        }
    }
}

// ---------------------------------------------------------------- flash MFMA attention
__global__ __launch_bounds__(256) void attn_mfma(const unsigned short* __restrict__ qkv,
                                                 const unsigned short* __restrict__ vT,
                                                 unsigned short* __restrict__ outb) {
    __shared__ alignas(16) unsigned short lds[40960];    // 81920 B
    unsigned short* KtP = lds;            // Kt [320][64] swizzled / P [64][320] swizzled
    unsigned short* Vt  = lds + 20480;    // [64][320] swizzled

    const int raw  = blockIdx.x + (blockIdx.y << 6);   // gridDim = (64,16)
    const int xcd  = raw & 7;
    const int slot = raw >> 3;
    const int q0   = (xcd * 8 + (slot & 7)) * 64;
    const int h    = slot >> 3;

    const int tid  = threadIdx.x;
    const int w    = tid >> 6;
    const int lane = tid & 63;
    const int quad = lane >> 4;
    const int l16  = lane & 15;
    const int kbase = q0 - 256;

    const unsigned short* qrow = qkv + (size_t)(q0 + w * 16 + l16) * 3072 + h * 64;
    short8 aq[2];
    aq[0] = *reinterpret_cast<const short8*>(qrow + quad * 8);
    aq[1] = *reinterpret_cast<const short8*>(qrow + 32 + quad * 8);

    #pragma unroll
    for (int i = 0; i < 10; ++i) {
        const int fc  = i * 256 + tid;
        const int row = fc >> 3, p = fc & 7;
        const int c   = p ^ (row & 7);
        int j = kbase + row; if (j < 0) j = 0;
        gld_lds16(qkv + (size_t)j * 3072 + EMB + h * 64 + c * 8,
                  KtP + (i * 256 + w * 64) * 8);
    }

    __syncthreads();

    #pragma unroll
    for (int i = 0; i < 10; ++i) {
        const int fc = i * 256 + tid;
        const int d  = fc / 40, pp = fc % 40;
        const int cc = (pp & ~7) | ((pp & 7) ^ (d & 7));
        int j0 = kbase + cc * 8; if (j0 < 0) j0 = 0;
        gld_lds16(vT + (size_t)(h * 64 + d) * S_LEN + j0,
                  Vt + (i * 256 + w * 64) * 8);
    }

    f32x4 accs[17];
    #pragma unroll
    for (int nb = 0; nb < 17; ++nb) accs[nb] = (f32x4){0.f, 0.f, 0.f, 0.f};

    #pragma unroll
    for (int ks = 0; ks < 2; ++ks)
        #pragma unroll
        for (int nb = 0; nb < 17; ++nb) {
            const int row = (w + nb) * 16 + l16;
            const int p   = (ks * 4 + quad) ^ (l16 & 7);
            const short8 bfr = *reinterpret_cast<const short8*>(&KtP[row * 64 + p * 8]);
            accs[nb] = __builtin_amdgcn_mfma_f32_16x16x32_bf16(aq[ks], bfr, accs[nb], 0, 0, 0);
        }

    __syncthreads();

    const int i0 = q0 + w * 16 + quad * 4;
    const int rw0 = w * 16 + quad * 4;
    float rsum[4] = {0.f, 0.f, 0.f, 0.f};
    #pragma unroll
    for (int nb = 0; nb < 17; ++nb) {
        const int t   = w + nb;
        const int j   = kbase + t * 16 + l16;
        const int cch = (t * 16 + l16) >> 3, e = l16 & 7;
        #pragma unroll
        for (int r = 0; r < 4; ++r) {
            const int i = i0 + r;
            const bool ok = (j >= 0) & (j <= i) & (j > i - WIN);
            const float ev = ok ? __expf(accs[nb][r]) : 0.f;
            rsum[r] += ev;
            const int rw  = rw0 + r;
            const int pos = (cch & ~7) | ((cch & 7) ^ (rw & 7));
            KtP[rw * 320 + pos * 8 + e] = f2b(ev);
        }
    }
    {
        const int tz = (w & 1) ? (w - 1) : (w + 17);
        const int cch = (tz * 16 + l16) >> 3, e = l16 & 7;
        #pragma unroll
        for (int r = 0; r < 4; ++r) {
            const int rw  = rw0 + r;
            const int pos = (cch & ~7) | ((cch & 7) ^ (rw & 7));
            KtP[rw * 320 + pos * 8 + e] = 0;
        }
    }
    float inv[4];
    #pragma unroll
    for (int r = 0; r < 4; ++r) {
        float s = rsum[r];
        #pragma unroll
        for (int off = 1; off < 16; off <<= 1)
            s += __shfl_xor(s, off, 64);
        inv[r] = 1.f / s;
    }

    f32x4 acco[4];
    #pragma unroll
    for (int nb2 = 0; nb2 < 4; ++nb2) acco[nb2] = (f32x4){0.f, 0.f, 0.f, 0.f};

    const int ks0 = w >> 1;
    #pragma unroll
    for (int ksi = 0; ksi < 9; ++ksi) {
        const int ks   = ks0 + ksi;
        const int prow = w * 16 + l16;
        const int cc   = ks * 4 + quad;
        const int ppos = (cc & ~7) | ((cc & 7) ^ (prow & 7));
        const short8 af = *reinterpret_cast<const short8*>(&KtP[prow * 320 + ppos * 8]);
        #pragma unroll
        for (int nb2 = 0; nb2 < 4; ++nb2) {
            const int d    = nb2 * 16 + l16;
            const int vpos = (cc & ~7) | ((cc & 7) ^ (d & 7));
            const short8 bfr = *reinterpret_cast<const short8*>(&Vt[d * 320 + vpos * 8]);
            acco[nb2] = __builtin_amdgcn_mfma_f32_16x16x32_bf16(af, bfr, acco[nb2], 0, 0, 0);
        }
    }

    #pragma unroll
    for (int nb2 = 0; nb2 < 4; ++nb2)
        #pragma unroll
        for (int r = 0; r < 4; ++r)
            outb[(size_t)(q0 + w * 16 + quad * 4 + r) * EMB + h * 64 + nb2 * 16 + l16] =
                f2b(acco[nb2][r] * inv[r]);
}

// ---------------------------------------------------------------- launch
extern "C" void kernel_launch(void* const* d_in, const int* in_sizes, int n_in,
                              void* d_out, int out_size, void* d_ws, size_t ws_size,
                              hipStream_t stream) {
    const float* x     = (const float*)d_in[0];
    const float* w_qkv = (const float*)d_in[2];
    const float* w_out = (const float*)d_in[3];
    float* out = (float*)d_out;

    char* ws = (char*)d_ws;
    unsigned short* xb     = (unsigned short*)(ws);                 // [4096][1024] bf16
    unsigned short* wqkvT  = (unsigned short*)(ws + (8u  << 20));   // [3072][1024] bf16
    unsigned short* woutT  = (unsigned short*)(ws + (14u << 20));   // [1024][1024] bf16
    unsigned short* qkvb   = (unsigned short*)(ws + (16u << 20));   // [4096][3072] (Q,K; Q prescaled)
    unsigned short* attnb  = (unsigned short*)(ws + (48u << 20));   // [4096][1024] bf16
    unsigned short* vT     = (unsigned short*)(ws + (56u << 20));   // [1024][4096] bf16

    prep<<<2048, 256, 0, stream>>>(x, xb, w_qkv, wqkvT, w_out, woutT);

    // qkv = x @ w_qkv ; Q (prescaled), K -> qkvb bf16, V -> vT transposed
    gemm_qkv<<<dim3(192), 512, 0, stream>>>(xb, wqkvT, qkvb, vT);

    attn_mfma<<<dim3(S_LEN / 64, NH), 256, 0, stream>>>(qkvb, vT, attnb);

    // out = attn @ w_out -> f32 (BN=64: 512 blocks = 2/CU)
    gemm_bt<0, 64><<<dim3(EMB / 64, S_LEN / 128), 256, 0, stream>>>(
        attnb, woutT, out, nullptr, S_LEN, EMB, EMB);
}